// Round 13
// baseline (184.530 us; speedup 1.0000x reference)
//
#include <hip/hip_runtime.h>
#include <math.h>

#define DIMC 64
#define NE 512
#define HWSZ 4096              // 64*64
#define NPTS 131072
#define DECAYF 0.99f
#define OMD 0.01f
#define EPSF 1e-5f
#define MARGIN 1e-3f

// output offsets (floats) — out0 is [32,64,64,64] = 8388608 elements
#define O0 0
#define O1 8388608                 // diff scalar
#define O2 8388609                 // embed_ind [32,64,64]
#define O3 8519681                 // new_cluster_size [512]
#define O4 8520193                 // new_dictionary_avg [64,512]
#define O5 8552961                 // new_dictionary [64,512]
#define O6 8585729                 // mean_D scalar

// ws float-offset layout
#define WS_DIFF   0
#define WS_ESUM   64                       // [c][j] 64*512 f32 (reduced)
#define WS_COUNTS 32832                    // 512 f32 (contiguous after ESUM)
#define WS_DT     33344                    // [j][c] dictT f32, 32768
#define WS_NORM   66112                    // 512: -0.5*||d_j||^2
#define WS_DHI    66624                    // 512x64 bf16 (16384 floats)
#define WS_DLO    83008                    // 512x64 bf16
#define WS_PART   246852                   // bf16 partials: NBLK2 x 33280 ushorts
#define PART_USH  33280                    // 32768 esum + 512 counts (ushorts)
#define NBLK2 512
#define WS_NEED_BYTES ((size_t)WS_PART * 4 + (size_t)NBLK2 * PART_USH * 2)

#define STG_STRIDE 144                     // 128 B row + 16 B pad (bank spread)

typedef __attribute__((ext_vector_type(8))) short bf16x8;
typedef __attribute__((ext_vector_type(4))) float f32x4;

__device__ __forceinline__ unsigned bf16rne(float x) {
    unsigned u = __float_as_uint(x);
    return (u + 0x7FFFu + ((u >> 16) & 1u)) >> 16;
}
__device__ __forceinline__ float f4c(const float4 v, int i) {
    return i == 0 ? v.x : i == 1 ? v.y : i == 2 ? v.z : v.w;
}

// -------- K1: dictT f32 + bf16 hi/lo + norms + zero accumulators --------
__global__ void k_prep(const float* __restrict__ dict, float* __restrict__ ws) {
    int j = blockIdx.x, c = threadIdx.x;
    float v = dict[c * NE + j];
    ws[WS_DT + j * DIMC + c] = v;
    unsigned h = bf16rne(v);
    float fh = __uint_as_float(h << 16);
    unsigned l = bf16rne(v - fh);
    ((unsigned short*)(ws + WS_DHI))[j * DIMC + c] = (unsigned short)h;
    ((unsigned short*)(ws + WS_DLO))[j * DIMC + c] = (unsigned short)l;
    // zero accumulators (fallback path + diff)
    ws[WS_ESUM + j * DIMC + c] = 0.f;
    if (c == 0) ws[WS_COUNTS + j] = 0.f;
    if (j == 0 && c == 0) ws[WS_DIFF] = 0.f;
    float s = v * v;
    #pragma unroll
    for (int off = 32; off > 0; off >>= 1) s += __shfl_down(s, off);
    if (c == 0) ws[WS_NORM + j] = -0.5f * s;
}

#define MFMA16(A, B, C) __builtin_amdgcn_mfma_f32_16x16x32_bf16(A, B, C, 0, 0, 0)

// -------- K2: fused score + in-block exact rescan + emit + partials -----
// 512 blocks x 512 threads; block covers 256 points; 2 blocks/CU.
__global__ __launch_bounds__(512, 4) void k_main(
        const float* __restrict__ x, float* __restrict__ ws,
        float* __restrict__ out, int use_part) {
    extern __shared__ float lds[];
    char*  stg    = (char*)lds;            // staging: 256 rows x 144 B = 36 KB
    float* eh     = lds;                   // 64KB esum half [32][512] f32
    int*   lhist  = (int*)(lds + 16384);   // 512
    int*   bidxl  = (int*)(lds + 16896);   // 256
    int*   lflist = (int*)(lds + 17152);   // 256
    int*   lcnt   = (int*)(lds + 17408);   // 1
    float* lred   = lds + 17412;           // 8

    const int tid  = threadIdx.x;
    const int lane = tid & 63;
    const int w    = tid >> 6;
    const int pg   = tid & 63;             // point-group of 4
    const int co   = tid >> 6;             // c-octant (8 c's)
    const int nb   = blockIdx.x * 256;
    const int b    = nb >> 12;
    const int hwb  = nb & 4095;

    lhist[tid] = 0;
    if (tid == 0) lcnt[0] = 0;

    const float* xio = x + (size_t)b * (DIMC * HWSZ)
                         + (size_t)(8 * co) * HWSZ + hwb + 4 * pg;

    // ---- load x (4 points x 8 c as float4): KEPT LIVE through kernel ----
    float4 xa[8];
    #pragma unroll
    for (int cc = 0; cc < 8; ++cc) xa[cc] = *(const float4*)(xio + (size_t)cc * HWSZ);

    // ---- bf16 split; stage hi chunks (row = i*64+pg, conflict-free) ----
    unsigned lw[4][4];
    #pragma unroll
    for (int i = 0; i < 4; ++i) {
        unsigned hw4[4];
        #pragma unroll
        for (int c2 = 0; c2 < 4; ++c2) {
            float v0 = f4c(xa[2 * c2], i), v1 = f4c(xa[2 * c2 + 1], i);
            unsigned h0 = bf16rne(v0), h1 = bf16rne(v1);
            float r0 = v0 - __uint_as_float(h0 << 16);
            float r1 = v1 - __uint_as_float(h1 << 16);
            hw4[c2] = h0 | (h1 << 16);
            lw[i][c2] = bf16rne(r0) | (bf16rne(r1) << 16);
        }
        uint4 u = {hw4[0], hw4[1], hw4[2], hw4[3]};
        *(uint4*)(stg + (i * 64 + pg) * STG_STRIDE + co * 16) = u;
    }
    __syncthreads();

    // ---- A-fragments hi: point p' = w*32+pt*16+(lane&15); row=rho(p') ----
    bf16x8 ahi[2][2], alo[2][2];
    #pragma unroll
    for (int pt = 0; pt < 2; ++pt) {
        const int pp = (w << 5) + (pt << 4) + (lane & 15);
        const int row = ((pp & 3) << 6) + (pp >> 2);
        #pragma unroll
        for (int kk = 0; kk < 2; ++kk) {
            const int ch = (lane >> 4) + (kk << 2);
            ahi[pt][kk] = __builtin_bit_cast(bf16x8,
                *(const uint4*)(stg + row * STG_STRIDE + ch * 16));
        }
    }
    __syncthreads();

    // ---- stage lo, extract ----
    #pragma unroll
    for (int i = 0; i < 4; ++i) {
        uint4 u = {lw[i][0], lw[i][1], lw[i][2], lw[i][3]};
        *(uint4*)(stg + (i * 64 + pg) * STG_STRIDE + co * 16) = u;
    }
    __syncthreads();
    #pragma unroll
    for (int pt = 0; pt < 2; ++pt) {
        const int pp = (w << 5) + (pt << 4) + (lane & 15);
        const int row = ((pp & 3) << 6) + (pp >> 2);
        #pragma unroll
        for (int kk = 0; kk < 2; ++kk) {
            const int ch = (lane >> 4) + (kk << 2);
            alo[pt][kk] = __builtin_bit_cast(bf16x8,
                *(const uint4*)(stg + row * STG_STRIDE + ch * 16));
        }
    }
    __syncthreads();

    // ---- MFMA sweep over 32 code-tiles ----
    const uint4* dh4 = (const uint4*)(ws + WS_DHI);
    const uint4* dl4 = (const uint4*)(ws + WS_DLO);
    const float* npl = ws + WS_NORM + (lane & 15);
    const int bl = ((lane & 15) << 3) + (lane >> 4);

    float best[2][4], sec[2][4];
    int   idx[2][4];
    #pragma unroll
    for (int pt = 0; pt < 2; ++pt)
        #pragma unroll
        for (int r = 0; r < 4; ++r) {
            best[pt][r] = -3.4e38f; sec[pt][r] = -3.4e38f; idx[pt][r] = 0;
        }

    #pragma unroll 2
    for (int jt = 0; jt < 32; ++jt) {
        uint4 uh0 = dh4[(jt << 7) + bl];
        uint4 uh1 = dh4[(jt << 7) + bl + 4];
        uint4 ul0 = dl4[(jt << 7) + bl];
        uint4 ul1 = dl4[(jt << 7) + bl + 4];
        float nrm = npl[jt << 4];
        bf16x8 bh0 = __builtin_bit_cast(bf16x8, uh0);
        bf16x8 bh1 = __builtin_bit_cast(bf16x8, uh1);
        bf16x8 bl0 = __builtin_bit_cast(bf16x8, ul0);
        bf16x8 bl1 = __builtin_bit_cast(bf16x8, ul1);
        const int jc = (jt << 4) + (lane & 15);
        #pragma unroll
        for (int pt = 0; pt < 2; ++pt) {
            f32x4 acc = {0.f, 0.f, 0.f, 0.f};
            acc = MFMA16(ahi[pt][0], bh0, acc);
            acc = MFMA16(ahi[pt][1], bh1, acc);
            acc = MFMA16(ahi[pt][0], bl0, acc);
            acc = MFMA16(ahi[pt][1], bl1, acc);
            acc = MFMA16(alo[pt][0], bh0, acc);
            acc = MFMA16(alo[pt][1], bh1, acc);
            acc = MFMA16(alo[pt][0], bl0, acc);
            acc = MFMA16(alo[pt][1], bl1, acc);
            #pragma unroll
            for (int r = 0; r < 4; ++r) {
                float s = acc[r] + nrm;
                bool gt = s > best[pt][r];
                float ns = gt ? best[pt][r] : (s > sec[pt][r] ? s : sec[pt][r]);
                best[pt][r] = gt ? s : best[pt][r];
                idx[pt][r]  = gt ? jc : idx[pt][r];
                sec[pt][r]  = ns;
            }
        }
    }

    // ---- argmax reduce across 16-lane code groups ----
    #pragma unroll
    for (int off = 8; off > 0; off >>= 1) {
        #pragma unroll
        for (int pt = 0; pt < 2; ++pt)
            #pragma unroll
            for (int r = 0; r < 4; ++r) {
                float ob = __shfl_xor(best[pt][r], off, 16);
                float os = __shfl_xor(sec[pt][r], off, 16);
                int   oi = __shfl_xor(idx[pt][r], off, 16);
                bool take = (ob > best[pt][r]) ||
                            (ob == best[pt][r] && oi < idx[pt][r]);
                float nsec = fmaxf(fminf(ob, best[pt][r]),
                                   fmaxf(os, sec[pt][r]));
                best[pt][r] = take ? ob : best[pt][r];
                idx[pt][r]  = take ? oi : idx[pt][r];
                sec[pt][r]  = nsec;
            }
    }
    if ((lane & 15) == 0) {
        const int g = lane >> 4;
        #pragma unroll
        for (int pt = 0; pt < 2; ++pt)
            #pragma unroll
            for (int r = 0; r < 4; ++r) {
                int p = (w << 5) + (pt << 4) + (g << 2) + r;
                int flag = (best[pt][r] - sec[pt][r] < MARGIN) ? 65536 : 0;
                bidxl[p] = idx[pt][r] | flag;
            }
    }
    __syncthreads();

    // ---- build flagged list ----
    if (tid < 256) {
        int e = bidxl[tid];
        if (e & 65536) {
            int pos = atomicAdd(lcnt, 1);
            lflist[pos] = tid;
        }
    }
    __syncthreads();

    // ---- in-block exact rescan, one wave per flagged point ----
    const float* dptr = ws + WS_DT;
    {
        const int nf = lcnt[0];
        for (int fi = w; fi < nf; fi += 8) {
            const int pp = lflist[fi];
            const float xv = x[(size_t)b * (DIMC * HWSZ)
                               + (size_t)lane * HWSZ + hwb + pp];
            float fj[DIMC];
            #pragma unroll
            for (int c = 0; c < DIMC; ++c) fj[c] = __shfl(xv, c);

            float bb = -3.4e38f; int bj = 0;
            #pragma unroll 2
            for (int s = 0; s < 8; ++s) {
                const int j = (lane << 3) + s;
                const float4* row = (const float4*)(dptr + (size_t)j * DIMC);
                float a0 = 0.f, a1 = 0.f, a2 = 0.f, a3 = 0.f;
                #pragma unroll
                for (int c4 = 0; c4 < 16; ++c4) {
                    float4 r4 = row[c4];
                    const int cb = 4 * c4;
                    a0 = fmaf(r4.x, fj[cb + 0], a0);
                    a1 = fmaf(r4.y, fj[cb + 1], a1);
                    a2 = fmaf(r4.z, fj[cb + 2], a2);
                    a3 = fmaf(r4.w, fj[cb + 3], a3);
                }
                float sc = ((a0 + a1) + (a2 + a3)) + ws[WS_NORM + j];
                if (sc > bb) { bb = sc; bj = j; }
            }
            #pragma unroll
            for (int off = 1; off < 64; off <<= 1) {
                float ob = __shfl_xor(bb, off);
                int   oi = __shfl_xor(bj, off);
                bool take = (ob > bb) || (ob == bb && oi < bj);
                bb = take ? ob : bb;
                bj = take ? oi : bj;
            }
            if (lane == 0) bidxl[pp] = bj;
        }
    }
    __syncthreads();

    // ---- emit (c-octant view): bidx, hist, embed_ind, quantize, diff ----
    int bi[4];
    #pragma unroll
    for (int i = 0; i < 4; ++i) bi[i] = bidxl[4 * pg + i] & 511;
    if (co == 0) {
        #pragma unroll
        for (int i = 0; i < 4; ++i) {
            atomicAdd(&lhist[bi[i]], 1);
            out[O2 + nb + 4 * pg + i] = (float)bi[i];
        }
    }

    // gather q rows (f32 exact); xa still live
    float4 qa[8];
    #pragma unroll
    for (int i = 0; i < 4; ++i)
        #pragma unroll
        for (int u = 0; u < 2; ++u)
            qa[2 * i + u] = *(const float4*)(dptr + (size_t)bi[i] * DIMC + 8 * co + 4 * u);

    float ssum = 0.f;
    #pragma unroll
    for (int i = 0; i < 4; ++i)
        #pragma unroll
        for (int u = 0; u < 2; ++u)
            #pragma unroll
            for (int e = 0; e < 4; ++e) {
                float d = f4c(qa[2 * i + u], e) - f4c(xa[4 * u + e], i);
                ssum = fmaf(d, d, ssum);
            }

    // out0: float4 per c (4 consecutive points)
    float* o0 = out + O0 + (size_t)b * (DIMC * HWSZ)
                    + (size_t)(8 * co) * HWSZ + hwb + 4 * pg;
    #pragma unroll
    for (int cc = 0; cc < 8; ++cc) {
        float4 o;
        o.x = f4c(qa[0 + (cc >> 2)], cc & 3);
        o.y = f4c(qa[2 + (cc >> 2)], cc & 3);
        o.z = f4c(qa[4 + (cc >> 2)], cc & 3);
        o.w = f4c(qa[6 + (cc >> 2)], cc & 3);
        *(float4*)(o0 + (size_t)cc * HWSZ) = o;
    }

    // ---- esum in two 64KB half-passes + bf16 partial write ----
    ushort* pB = (ushort*)(ws + WS_PART) + (size_t)blockIdx.x * PART_USH;
    for (int h = 0; h < 2; ++h) {
        __syncthreads();
        {
            float4 z = {0.f, 0.f, 0.f, 0.f};
            #pragma unroll
            for (int k = 0; k < 8; ++k) ((float4*)eh)[tid + 512 * k] = z;
        }
        __syncthreads();
        if ((co >> 2) == h) {
            #pragma unroll
            for (int cc = 0; cc < 8; ++cc) {
                const int cp = (8 * co + cc - 32 * h) * NE;
                #pragma unroll
                for (int i = 0; i < 4; ++i)
                    atomicAdd(&eh[cp + bi[i]], f4c(xa[cc], i));
            }
        }
        __syncthreads();
        if (use_part) {
            ushort* ph = pB + h * 16384;
            #pragma unroll
            for (int k = 0; k < 8; ++k) {
                float4 a = ((const float4*)eh)[tid + 512 * k];
                uint2 u;
                u.x = bf16rne(a.x) | (bf16rne(a.y) << 16);
                u.y = bf16rne(a.z) | (bf16rne(a.w) << 16);
                *(uint2*)(ph + 4 * (tid + 512 * k)) = u;
            }
        } else {
            #pragma unroll
            for (int k = 0; k < 8; ++k) {
                float4 a = ((const float4*)eh)[tid + 512 * k];
                const int fi = h * 16384 + 4 * (tid + 512 * k);
                atomicAdd(&ws[WS_ESUM + fi + 0], a.x);
                atomicAdd(&ws[WS_ESUM + fi + 1], a.y);
                atomicAdd(&ws[WS_ESUM + fi + 2], a.z);
                atomicAdd(&ws[WS_ESUM + fi + 3], a.w);
            }
        }
    }
    __syncthreads();
    if (use_part) {
        pB[32768 + tid] = (ushort)bf16rne((float)lhist[tid]);
    } else {
        atomicAdd(&ws[WS_COUNTS + tid], (float)lhist[tid]);
    }

    // diff reduction
    #pragma unroll
    for (int off = 32; off > 0; off >>= 1) ssum += __shfl_down(ssum, off);
    if ((tid & 63) == 0) lred[tid >> 6] = ssum;
    __syncthreads();
    if (tid == 0) {
        float t = 0.f;
        #pragma unroll
        for (int w2 = 0; w2 < 8; ++w2) t += lred[w2];
        atomicAdd(ws + WS_DIFF, t);
    }
}

// -------- K2d: reduce bf16 partials (512 blocks) into f32 ESUM/COUNTS ---
__global__ void k_reduce(float* __restrict__ ws) {
    __shared__ float ex[128][8];
    const int tid = threadIdx.x;
    const int g2 = blockIdx.x * 256 + tid;
    const int pos = g2 >> 1, half = g2 & 1;
    const bool act = pos < 4160;             // 33280 ushorts / 8 per uint4
    const uint4* pb = (const uint4*)((const ushort*)(ws + WS_PART));
    float acc[8];
    #pragma unroll
    for (int k = 0; k < 8; ++k) acc[k] = 0.f;
    if (act) {
        const int p0 = half * 256;
        for (int p = p0; p < p0 + 256; ++p) {
            uint4 v = pb[(size_t)p * 4160 + pos];
            acc[0] += __uint_as_float(v.x << 16);
            acc[1] += __uint_as_float(v.x & 0xffff0000u);
            acc[2] += __uint_as_float(v.y << 16);
            acc[3] += __uint_as_float(v.y & 0xffff0000u);
            acc[4] += __uint_as_float(v.z << 16);
            acc[5] += __uint_as_float(v.z & 0xffff0000u);
            acc[6] += __uint_as_float(v.w << 16);
            acc[7] += __uint_as_float(v.w & 0xffff0000u);
        }
    }
    if (act && half) {
        #pragma unroll
        for (int k = 0; k < 8; ++k) ex[tid >> 1][k] = acc[k];
    }
    __syncthreads();
    if (act && !half) {
        #pragma unroll
        for (int k = 0; k < 8; ++k) acc[k] += ex[tid >> 1][k];
        float4 r0 = {acc[0], acc[1], acc[2], acc[3]};
        float4 r1 = {acc[4], acc[5], acc[6], acc[7]};
        ((float4*)(ws + WS_ESUM))[pos * 2]     = r0;
        ((float4*)(ws + WS_ESUM))[pos * 2 + 1] = r1;
    }
}

// -------- K3: finalize EMA buffers / outputs --------
__global__ void k_final(const float* __restrict__ ws,
                        const float* __restrict__ cluster_size,
                        const float* __restrict__ davg,
                        float* __restrict__ out) {
    __shared__ float red[16];
    __shared__ float nsh;
    const int j = threadIdx.x;

    float cnt = ws[WS_COUNTS + j];
    float ncs = DECAYF * cluster_size[j] + OMD * cnt;
    out[O3 + j] = ncs;

    float v = ncs;
    #pragma unroll
    for (int off = 32; off > 0; off >>= 1) v += __shfl_down(v, off);
    if ((j & 63) == 0) red[j >> 6] = v;
    __syncthreads();
    if (j == 0) {
        float t = 0.f;
        #pragma unroll
        for (int w = 0; w < 8; ++w) t += red[w];
        nsh = t;
    }
    __syncthreads();
    const float n = nsh;
    const float csj = (ncs + EPSF) / (n + NE * EPSF) * n;

    float asum = 0.f;
    #pragma unroll
    for (int c = 0; c < DIMC; ++c) {
        float es = ws[WS_ESUM + c * NE + j];
        float da = davg[c * NE + j];
        float nda = DECAYF * da + OMD * es;
        out[O4 + c * NE + j] = nda;
        float nd = nda / csj;
        out[O5 + c * NE + j] = nd;
        asum += fabsf(nd);
    }

    __syncthreads();
    #pragma unroll
    for (int off = 32; off > 0; off >>= 1) asum += __shfl_down(asum, off);
    if ((j & 63) == 0) red[j >> 6] = asum;
    __syncthreads();
    if (j == 0) {
        float t = 0.f;
        #pragma unroll
        for (int w = 0; w < 8; ++w) t += red[w];
        out[O6] = t / 32768.0f;
        out[O1] = ws[WS_DIFF] / 8388608.0f;
    }
}

extern "C" void kernel_launch(void* const* d_in, const int* in_sizes, int n_in,
                              void* d_out, int out_size, void* d_ws, size_t ws_size,
                              hipStream_t stream) {
    const float* x    = (const float*)d_in[0];
    const float* dict = (const float*)d_in[1];
    const float* csz  = (const float*)d_in[2];
    const float* davg = (const float*)d_in[3];
    float* out = (float*)d_out;
    float* ws  = (float*)d_ws;

    const int use_part = (ws_size >= WS_NEED_BYTES) ? 1 : 0;

    k_prep<<<512, 64, 0, stream>>>(dict, ws);

    const int main_lds = 17420 * 4;   // 69.7 KB -> 2 blocks/CU
    hipFuncSetAttribute((const void*)k_main,
                        hipFuncAttributeMaxDynamicSharedMemorySize, main_lds);
    k_main<<<NBLK2, 512, main_lds, stream>>>(x, ws, out, use_part);

    if (use_part) k_reduce<<<33, 256, 0, stream>>>(ws);

    k_final<<<1, 512, 0, stream>>>(ws, csz, davg, out);
}

// Round 14
// 146.950 us; speedup vs baseline: 1.2557x; 1.2557x over previous
//
#include <hip/hip_runtime.h>
#include <math.h>

#define DIMC 64
#define NE 512
#define HWSZ 4096              // 64*64
#define NPTS 131072
#define DECAYF 0.99f
#define OMD 0.01f
#define EPSF 1e-5f
#define MARGIN 1e-3f

// output offsets (floats) — out0 is [32,64,64,64] = 8388608 elements
#define O0 0
#define O1 8388608                 // diff scalar
#define O2 8388609                 // embed_ind [32,64,64]
#define O3 8519681                 // new_cluster_size [512]
#define O4 8520193                 // new_dictionary_avg [64,512]
#define O5 8552961                 // new_dictionary [64,512]
#define O6 8585729                 // mean_D scalar

// ws float-offset layout (r11-proven)
#define WS_DIFF   0
#define WS_ESUM   64                       // [c][j] 64*512 f32 (reduced)
#define WS_COUNTS 32832                    // 512 f32 (contiguous after ESUM)
#define WS_DT     33344                    // [j][c] dictT f32, 32768
#define WS_NORM   66112                    // 512: -0.5*||d_j||^2
#define WS_DHI    66624                    // 512x64 bf16 (16384 floats)
#define WS_DLO    83008                    // 512x64 bf16
#define WS_PART   246852                   // f32 partials: NBLK x 33280
#define PART_STRIDE 33280                  // 32768 esum + 512 counts
#define NBLK 256
#define WS_NEED_BYTES ((size_t)(WS_PART + (size_t)NBLK * PART_STRIDE) * 4)

typedef __attribute__((ext_vector_type(8))) short bf16x8;
typedef __attribute__((ext_vector_type(4))) float f32x4;

__device__ __forceinline__ unsigned bf16rne(float x) {
    unsigned u = __float_as_uint(x);
    return (u + 0x7FFFu + ((u >> 16) & 1u)) >> 16;
}

// -------- K1: dictT f32 + bf16 hi/lo + norms + zero accumulators --------
__global__ void k_prep(const float* __restrict__ dict, float* __restrict__ ws) {
    int j = blockIdx.x, c = threadIdx.x;
    float v = dict[c * NE + j];
    ws[WS_DT + j * DIMC + c] = v;
    unsigned h = bf16rne(v);
    float fh = __uint_as_float(h << 16);
    unsigned l = bf16rne(v - fh);
    ((unsigned short*)(ws + WS_DHI))[j * DIMC + c] = (unsigned short)h;
    ((unsigned short*)(ws + WS_DLO))[j * DIMC + c] = (unsigned short)l;
    // zero accumulators (fallback path + diff)
    ws[WS_ESUM + j * DIMC + c] = 0.f;
    if (c == 0) ws[WS_COUNTS + j] = 0.f;
    if (j == 0 && c == 0) ws[WS_DIFF] = 0.f;
    float s = v * v;
    #pragma unroll
    for (int off = 32; off > 0; off >>= 1) s += __shfl_down(s, off);
    if (c == 0) ws[WS_NORM + j] = -0.5f * s;
}

#define MFMA16(A, B, C) __builtin_amdgcn_mfma_f32_16x16x32_bf16(A, B, C, 0, 0, 0)

// -------- K2: fused MFMA score + in-block exact rescan + emit + partials --
// 256 blocks x 512 threads (8 waves); wave computes 64 points x 512 codes.
// Structure identical to the measured-105us r11 kernel; rescan replaces the
// provisional-emit/patch machinery.
__global__ __launch_bounds__(512, 1) void k_main(
        const float* __restrict__ x, float* __restrict__ ws,
        float* __restrict__ out, int use_part) {
    extern __shared__ float lds[];
    char*  ldsB   = (char*)lds;          // phase1: hi[512][64]bf16 | lo (128 KB)
    float* esum   = lds;                 // phase2: esum_t [c][j] 64x512 f32
    int*   lhist  = (int*)(lds + 32768); // 512
    int*   bidxl  = (int*)(lds + 33280); // 512
    int*   lflist = (int*)(lds + 33792); // 512
    int*   lcnt   = (int*)(lds + 34304); // 1
    float* lred   = lds + 34308;         // 8

    const int tid  = threadIdx.x;
    const int lane = tid & 63;
    const int w    = tid >> 6;

    const int nb = blockIdx.x * 512;
    const int n0 = nb + tid;
    const int b = n0 >> 12, hw0 = n0 & 4095;
    const float* xp = x + (size_t)b * (DIMC * HWSZ) + hw0;

    // ---- load point + bf16 split + stage to LDS (chunk-XOR swizzled) ----
    float f0[DIMC];
    #pragma unroll
    for (int c = 0; c < DIMC; ++c) f0[c] = xp[c * HWSZ];
    {
        unsigned hiw[32], low[32];
        #pragma unroll
        for (int i = 0; i < 32; ++i) {
            unsigned h0 = bf16rne(f0[2 * i]);
            unsigned h1 = bf16rne(f0[2 * i + 1]);
            float fh0 = __uint_as_float(h0 << 16);
            float fh1 = __uint_as_float(h1 << 16);
            unsigned l0 = bf16rne(f0[2 * i] - fh0);
            unsigned l1 = bf16rne(f0[2 * i + 1] - fh1);
            hiw[i] = h0 | (h1 << 16);
            low[i] = l0 | (l1 << 16);
        }
        const int swz = tid & 7;
        #pragma unroll
        for (int k = 0; k < 8; ++k) {
            uint4 vh = {hiw[4 * k], hiw[4 * k + 1], hiw[4 * k + 2], hiw[4 * k + 3]};
            uint4 vl = {low[4 * k], low[4 * k + 1], low[4 * k + 2], low[4 * k + 3]};
            *(uint4*)(ldsB + tid * 128 + ((k ^ swz) << 4)) = vh;
            *(uint4*)(ldsB + 65536 + tid * 128 + ((k ^ swz) << 4)) = vl;
        }
    }
    lhist[tid] = 0;
    if (tid == 0) lcnt[0] = 0;
    __syncthreads();

    // ---- A-fragments (row = lane&15, k = (lane>>4)*8 + e, +32*kk) ----
    bf16x8 ahi[4][2], alo[4][2];
    #pragma unroll
    for (int pt = 0; pt < 4; ++pt) {
        const int arow = (w << 6) + (pt << 4) + (lane & 15);
        const int swz = arow & 7;
        #pragma unroll
        for (int kk = 0; kk < 2; ++kk) {
            const int ch = (lane >> 4) + (kk << 2);
            ahi[pt][kk] = __builtin_bit_cast(bf16x8,
                *(const uint4*)(ldsB + arow * 128 + ((ch ^ swz) << 4)));
            alo[pt][kk] = __builtin_bit_cast(bf16x8,
                *(const uint4*)(ldsB + 65536 + arow * 128 + ((ch ^ swz) << 4)));
        }
    }
    __syncthreads();   // staging dead -> reuse as esum

    // zero esum region (overwrites staging)
    {
        float4 z = {0.f, 0.f, 0.f, 0.f};
        float4* e4 = (float4*)lds;
        #pragma unroll
        for (int k = 0; k < 16; ++k) e4[tid + 512 * k] = z;
    }

    // ---- MFMA sweep over 32 code-tiles ----
    const uint4* dh4 = (const uint4*)(ws + WS_DHI);
    const uint4* dl4 = (const uint4*)(ws + WS_DLO);
    const float* npl = ws + WS_NORM + (lane & 15);
    const int bl = ((lane & 15) << 3) + (lane >> 4);

    float best[4][4], sec[4][4];
    int   idx[4][4];
    #pragma unroll
    for (int pt = 0; pt < 4; ++pt)
        #pragma unroll
        for (int r = 0; r < 4; ++r) {
            best[pt][r] = -3.4e38f; sec[pt][r] = -3.4e38f; idx[pt][r] = 0;
        }

    #pragma unroll 2
    for (int jt = 0; jt < 32; ++jt) {
        uint4 uh0 = dh4[(jt << 7) + bl];
        uint4 uh1 = dh4[(jt << 7) + bl + 4];
        uint4 ul0 = dl4[(jt << 7) + bl];
        uint4 ul1 = dl4[(jt << 7) + bl + 4];
        float nrm = npl[jt << 4];
        bf16x8 bh0 = __builtin_bit_cast(bf16x8, uh0);
        bf16x8 bh1 = __builtin_bit_cast(bf16x8, uh1);
        bf16x8 bl0 = __builtin_bit_cast(bf16x8, ul0);
        bf16x8 bl1 = __builtin_bit_cast(bf16x8, ul1);
        const int jc = (jt << 4) + (lane & 15);
        #pragma unroll
        for (int pt = 0; pt < 4; ++pt) {
            f32x4 acc = {0.f, 0.f, 0.f, 0.f};
            acc = MFMA16(ahi[pt][0], bh0, acc);
            acc = MFMA16(ahi[pt][1], bh1, acc);
            acc = MFMA16(ahi[pt][0], bl0, acc);
            acc = MFMA16(ahi[pt][1], bl1, acc);
            acc = MFMA16(alo[pt][0], bh0, acc);
            acc = MFMA16(alo[pt][1], bh1, acc);
            acc = MFMA16(alo[pt][0], bl0, acc);
            acc = MFMA16(alo[pt][1], bl1, acc);
            #pragma unroll
            for (int r = 0; r < 4; ++r) {
                float s = acc[r] + nrm;
                bool gt = s > best[pt][r];
                float ns = gt ? best[pt][r] : (s > sec[pt][r] ? s : sec[pt][r]);
                best[pt][r] = gt ? s : best[pt][r];
                idx[pt][r]  = gt ? jc : idx[pt][r];
                sec[pt][r]  = ns;
            }
        }
    }

    // ---- argmax reduce across 16-lane code groups ----
    #pragma unroll
    for (int off = 8; off > 0; off >>= 1) {
        #pragma unroll
        for (int pt = 0; pt < 4; ++pt)
            #pragma unroll
            for (int r = 0; r < 4; ++r) {
                float ob = __shfl_xor(best[pt][r], off, 16);
                float os = __shfl_xor(sec[pt][r], off, 16);
                int   oi = __shfl_xor(idx[pt][r], off, 16);
                bool take = (ob > best[pt][r]) ||
                            (ob == best[pt][r] && oi < idx[pt][r]);
                float nsec = fmaxf(fminf(ob, best[pt][r]),
                                   fmaxf(os, sec[pt][r]));
                best[pt][r] = take ? ob : best[pt][r];
                idx[pt][r]  = take ? oi : idx[pt][r];
                sec[pt][r]  = nsec;
            }
    }
    if ((lane & 15) == 0) {
        const int g = lane >> 4;
        #pragma unroll
        for (int pt = 0; pt < 4; ++pt)
            #pragma unroll
            for (int r = 0; r < 4; ++r) {
                int p = (w << 6) + (pt << 4) + (g << 2) + r;
                int flag = (best[pt][r] - sec[pt][r] < MARGIN) ? 65536 : 0;
                bidxl[p] = idx[pt][r] | flag;
            }
    }
    __syncthreads();

    // ---- build flagged list ----
    {
        int e = bidxl[tid];
        if (e & 65536) {
            int pos = atomicAdd(lcnt, 1);
            lflist[pos] = tid;
        }
    }
    __syncthreads();

    // ---- in-block exact rescan, one wave per flagged point (inline shfl) --
    const float* dptr = ws + WS_DT;
    {
        const int nf = lcnt[0];
        const int hwb = nb & 4095;
        for (int fi = w; fi < nf; fi += 8) {
            const int pp = lflist[fi];
            const float xv = x[(size_t)b * (DIMC * HWSZ)
                               + (size_t)lane * HWSZ + hwb + pp];
            float bb = -3.4e38f; int bj = 0;
            #pragma unroll 2
            for (int s = 0; s < 8; ++s) {
                const int j = (lane << 3) + s;
                const float4* row = (const float4*)(dptr + (size_t)j * DIMC);
                float a0 = 0.f, a1 = 0.f, a2 = 0.f, a3 = 0.f;
                #pragma unroll
                for (int c4 = 0; c4 < 16; ++c4) {
                    float4 r4 = row[c4];
                    a0 = fmaf(r4.x, __shfl(xv, 4 * c4 + 0), a0);
                    a1 = fmaf(r4.y, __shfl(xv, 4 * c4 + 1), a1);
                    a2 = fmaf(r4.z, __shfl(xv, 4 * c4 + 2), a2);
                    a3 = fmaf(r4.w, __shfl(xv, 4 * c4 + 3), a3);
                }
                float sc = ((a0 + a1) + (a2 + a3)) + ws[WS_NORM + j];
                if (sc > bb) { bb = sc; bj = j; }
            }
            #pragma unroll
            for (int off = 1; off < 64; off <<= 1) {
                float ob = __shfl_xor(bb, off);
                int   oi = __shfl_xor(bj, off);
                bool take = (ob > bb) || (ob == bb && oi < bj);
                bb = take ? ob : bb;
                bj = take ? oi : bj;
            }
            if (lane == 0) bidxl[pp] = bj;
        }
    }
    __syncthreads();

    // ---- emit with FINAL indices: hist, embed_ind, quantize, diff, esum --
    const int bi0 = bidxl[tid] & 511;
    atomicAdd(&lhist[bi0], 1);
    out[O2 + n0] = (float)bi0;

    float ssum = 0.f;
    float* o0 = out + O0 + (size_t)b * (DIMC * HWSZ) + hw0;
    const float4* q40 = (const float4*)(dptr + (size_t)bi0 * DIMC);
    #pragma unroll
    for (int c4 = 0; c4 < 16; ++c4) {
        float4 qa = q40[c4];
        const int cb = 4 * c4;
        o0[(cb + 0) * HWSZ] = qa.x;
        o0[(cb + 1) * HWSZ] = qa.y;
        o0[(cb + 2) * HWSZ] = qa.z;
        o0[(cb + 3) * HWSZ] = qa.w;
        float d;
        d = qa.x - f0[cb + 0]; ssum = fmaf(d, d, ssum);
        d = qa.y - f0[cb + 1]; ssum = fmaf(d, d, ssum);
        d = qa.z - f0[cb + 2]; ssum = fmaf(d, d, ssum);
        d = qa.w - f0[cb + 3]; ssum = fmaf(d, d, ssum);
    }

    #pragma unroll
    for (int c = 0; c < DIMC; ++c) atomicAdd(&esum[c * NE + bi0], f0[c]);
    __syncthreads();

    if (use_part) {
        float* part = ws + WS_PART + (size_t)blockIdx.x * PART_STRIDE;
        float4* p4 = (float4*)part;
        const float4* e4 = (const float4*)esum;
        #pragma unroll
        for (int k = 0; k < 16; ++k) p4[tid + 512 * k] = e4[tid + 512 * k];
        part[32768 + tid] = (float)lhist[tid];
    } else {
        #pragma unroll
        for (int k = 0; k < 64; ++k)
            atomicAdd(&ws[WS_ESUM + tid + 512 * k], esum[tid + 512 * k]);
        atomicAdd(&ws[WS_COUNTS + tid], (float)lhist[tid]);
    }

    // diff reduction (8 waves)
    #pragma unroll
    for (int off = 32; off > 0; off >>= 1) ssum += __shfl_down(ssum, off);
    if ((tid & 63) == 0) lred[tid >> 6] = ssum;
    __syncthreads();
    if (tid == 0) {
        float t = 0.f;
        #pragma unroll
        for (int w2 = 0; w2 < 8; ++w2) t += lred[w2];
        atomicAdd(ws + WS_DIFF, t);
    }
}

// -------- K2d: tree-reduce per-block f32 partials into ESUM/COUNTS ------
__global__ void k_reduce(float* __restrict__ ws) {
    const int gid = blockIdx.x * 128 + threadIdx.x;   // [0, 8320)
    const float4* src = (const float4*)(ws + WS_PART);
    float4 acc = {0.f, 0.f, 0.f, 0.f};
    #pragma unroll 4
    for (int p = 0; p < NBLK; ++p) {
        float4 v = src[(size_t)p * (PART_STRIDE / 4) + gid];
        acc.x += v.x; acc.y += v.y; acc.z += v.z; acc.w += v.w;
    }
    ((float4*)(ws + WS_ESUM))[gid] = acc;   // COUNTS follows ESUM contiguously
}

// -------- K3: finalize EMA buffers / outputs --------
__global__ void k_final(const float* __restrict__ ws,
                        const float* __restrict__ cluster_size,
                        const float* __restrict__ davg,
                        float* __restrict__ out) {
    __shared__ float red[16];
    __shared__ float nsh;
    const int j = threadIdx.x;

    float cnt = ws[WS_COUNTS + j];
    float ncs = DECAYF * cluster_size[j] + OMD * cnt;
    out[O3 + j] = ncs;

    float v = ncs;
    #pragma unroll
    for (int off = 32; off > 0; off >>= 1) v += __shfl_down(v, off);
    if ((j & 63) == 0) red[j >> 6] = v;
    __syncthreads();
    if (j == 0) {
        float t = 0.f;
        #pragma unroll
        for (int w = 0; w < 8; ++w) t += red[w];
        nsh = t;
    }
    __syncthreads();
    const float n = nsh;
    const float csj = (ncs + EPSF) / (n + NE * EPSF) * n;

    float asum = 0.f;
    #pragma unroll
    for (int c = 0; c < DIMC; ++c) {
        float es = ws[WS_ESUM + c * NE + j];
        float da = davg[c * NE + j];
        float nda = DECAYF * da + OMD * es;
        out[O4 + c * NE + j] = nda;
        float nd = nda / csj;
        out[O5 + c * NE + j] = nd;
        asum += fabsf(nd);
    }

    __syncthreads();
    #pragma unroll
    for (int off = 32; off > 0; off >>= 1) asum += __shfl_down(asum, off);
    if ((j & 63) == 0) red[j >> 6] = asum;
    __syncthreads();
    if (j == 0) {
        float t = 0.f;
        #pragma unroll
        for (int w = 0; w < 8; ++w) t += red[w];
        out[O6] = t / 32768.0f;
        out[O1] = ws[WS_DIFF] / 8388608.0f;
    }
}

extern "C" void kernel_launch(void* const* d_in, const int* in_sizes, int n_in,
                              void* d_out, int out_size, void* d_ws, size_t ws_size,
                              hipStream_t stream) {
    const float* x    = (const float*)d_in[0];
    const float* dict = (const float*)d_in[1];
    const float* csz  = (const float*)d_in[2];
    const float* davg = (const float*)d_in[3];
    float* out = (float*)d_out;
    float* ws  = (float*)d_ws;

    const int use_part = (ws_size >= WS_NEED_BYTES) ? 1 : 0;

    k_prep<<<512, 64, 0, stream>>>(dict, ws);

    const int main_lds = 34320 * 4;   // 137.3 KB (1 block/CU)
    hipFuncSetAttribute((const void*)k_main,
                        hipFuncAttributeMaxDynamicSharedMemorySize, main_lds);
    k_main<<<NBLK, 512, main_lds, stream>>>(x, ws, out, use_part);

    if (use_part) k_reduce<<<65, 128, 0, stream>>>(ws);

    k_final<<<1, 512, 0, stream>>>(ws, csz, davg, out);
}